// Round 4
// baseline (2398.491 us; speedup 1.0000x reference)
//
#include <hip/hip_runtime.h>
#include <hip/hip_bf16.h>

#define HD 256
#define WD 256
#define CH 256
#define NB 2
#define NPIX (NB*HD*WD)

typedef __attribute__((ext_vector_type(4))) float f32x4;
typedef __attribute__((ext_vector_type(8))) short bf16x8;
typedef __attribute__((ext_vector_type(4))) short bf16x4;

__device__ __forceinline__ short f2bf(float f){
  unsigned u = __float_as_uint(f);
  u += 0x7fffu + ((u>>16)&1u);
  return (short)(u>>16);
}

__device__ __forceinline__ f32x4 mfma_bf16(bf16x8 a, bf16x8 b, f32x4 c){
  asm("v_mfma_f32_16x16x32_bf16 %0, %1, %2, %0" : "+v"(c) : "v"(a), "v"(b));
  return c;
}

// ---------------- weight fp32 -> bf16 ----------------
// layout (shorts): [0) qkv 196608 | [196608) proj 65536 | [262144) w1 262144 | [524288) w2 262144
__global__ __launch_bounds__(256) void k_cvtw(const float* __restrict__ qkvw,
    const float* __restrict__ projw, const float* __restrict__ w1,
    const float* __restrict__ w2, short* __restrict__ out){
  int i = blockIdx.x*256 + threadIdx.x;
  float v;
  if (i < 196608) v = qkvw[i];
  else if (i < 262144) v = projw[i-196608];
  else if (i < 524288) v = w1[i-262144];
  else v = w2[i-524288];
  out[i] = f2bf(v);
}

// ---------------- transpose conv weights to channel-minor ----------------
// wT layout (floats): [0) comb 49*512 (wi,i,o) | [25088) g 49*256 | [37632) h 49*256
//                     [50176) convf 9*256 (tap, oc*4+ic)
__global__ __launch_bounds__(256) void k_prepw(const float* __restrict__ combw,
    const float* __restrict__ gw, const float* __restrict__ hw,
    const float* __restrict__ fw, float* __restrict__ wT){
  int i = blockIdx.x*256 + threadIdx.x;
  if (i < 25088){
    int wi = i>>9, r = i&511, ii = r>>8, o = r&255;
    wT[i] = combw[o*98 + ii*49 + wi];
  } else if (i < 37632){
    int j = i-25088; int wi = j>>8, c = j&255;
    wT[i] = gw[c*49 + wi];
  } else if (i < 50176){
    int j = i-37632; int wi = j>>8, c = j&255;
    wT[i] = hw[c*49 + wi];
  } else if (i < 52480){
    int j = i-50176; int tap = j>>8, r = j&255, oc = r>>2, ic = r&3;
    wT[i] = fw[oc*36 + ic*9 + tap];
  }
}

// ---------------- depthwise 3x3 (NCHW in) + bias + relu + LN1 -> NHWC ----------------
__global__ __launch_bounds__(256) void k_conv3(const float* __restrict__ x,
    const float* __restrict__ w, const float* __restrict__ bias,
    const float* __restrict__ g1, const float* __restrict__ b1,
    float* __restrict__ out){
  // grid = 16 xb * 256 y * 2 b = 8192
  int bid = blockIdx.x;
  int xb = bid & 15, y = (bid>>4) & 255, b = bid>>12;
  int t = threadIdx.x;
  __shared__ float tile[16][268];
  int xx0 = xb*16;
  {
    int xi = t & 15, cg = t >> 4;
    int xxg = xx0 + xi;
    #pragma unroll
    for (int k=0;k<16;++k){
      int c = cg*16 + k;
      const float* xp = x + ((size_t)(b*CH + c)*HD)*WD;
      float acc = bias[c];
      #pragma unroll
      for (int dy=-1; dy<=1; ++dy){
        int yy = y+dy;
        if ((unsigned)yy >= HD) continue;
        #pragma unroll
        for (int dx=-1; dx<=1; ++dx){
          int x2 = xxg+dx;
          if ((unsigned)x2 >= WD) continue;
          acc += xp[yy*WD + x2] * w[c*9 + (dy+1)*3 + (dx+1)];
        }
      }
      tile[xi][c] = fmaxf(acc, 0.f);
    }
  }
  __syncthreads();
  {
    int px = t >> 4, cs = t & 15;
    float4 m[4];
    #pragma unroll
    for (int j=0;j<4;++j) m[j] = *(const float4*)(&tile[px][cs*16 + j*4]);
    float s = 0.f, q = 0.f;
    #pragma unroll
    for (int j=0;j<4;++j){
      s += m[j].x+m[j].y+m[j].z+m[j].w;
      q += m[j].x*m[j].x+m[j].y*m[j].y+m[j].z*m[j].z+m[j].w*m[j].w;
    }
    #pragma unroll
    for (int o=1;o<16;o<<=1){ s += __shfl_xor(s,o); q += __shfl_xor(q,o); }
    float mean = s*(1.f/CH);
    float r = rsqrtf(q*(1.f/CH) - mean*mean + 1e-5f);
    size_t n = (size_t)(b*HD + y)*WD + xx0 + px;
    float* op = out + n*CH + cs*16;
    #pragma unroll
    for (int j=0;j<4;++j){
      float4 G = *(const float4*)(g1 + cs*16 + j*4);
      float4 Bb = *(const float4*)(b1 + cs*16 + j*4);
      float4 o4;
      o4.x = (m[j].x-mean)*r*G.x + Bb.x;
      o4.y = (m[j].y-mean)*r*G.y + Bb.y;
      o4.z = (m[j].z-mean)*r*G.z + Bb.z;
      o4.w = (m[j].w-mean)*r*G.w + Bb.w;
      *(float4*)(op + j*4) = o4;
    }
  }
}

// ---------------- grouped 7x7 combine + relu + LN2 + fsaLN ----------------
// out channel o reads concat-channels 2o,2o+1; o<128 -> xconv, o>=128 -> h
__global__ __launch_bounds__(256,3) void k_comb(const float* __restrict__ xconv,
    const float* __restrict__ hbuf, const float* __restrict__ wT,
    const float* __restrict__ bias,
    const float* __restrict__ g2, const float* __restrict__ b2,
    const float* __restrict__ gf, const float* __restrict__ bfv,
    float* __restrict__ xc, short* __restrict__ ybuf){
  // grid = 64 xg * 32 yb * 2 b = 4096 ; wave: one x, 8 y, 4 out-ch per lane
  int bid = blockIdx.x;
  int xg = bid & 63, yb = (bid>>6) & 31, b = bid>>11;
  int wv = threadIdx.x>>6, lane = threadIdx.x & 63;
  int xx = xg*4 + wv, y0 = yb*8;
  const float* S = (lane < 32) ? xconv : hbuf;
  int cin = 8*(lane & 31);
  float4 bv = ((const float4*)bias)[lane];
  float4 acc[8];
  #pragma unroll
  for (int i=0;i<8;++i) acc[i] = bv;
  bool inty = (y0 >= 3) && (y0 <= HD-11);
  #pragma unroll 1
  for (int dx=0; dx<7; ++dx){
    int x2 = xx + dx - 3;
    bool vx = (unsigned)x2 < WD;
    float4 wa[7], wb4[7];
    #pragma unroll
    for (int dy=0; dy<7; ++dy){
      wa[dy]  = ((const float4*)(wT + (dy*7+dx)*512))[lane];
      wb4[dy] = ((const float4*)(wT + (dy*7+dx)*512 + 256))[lane];
    }
    if (vx && inty){
      const float* base = S + ((size_t)((b*HD + y0-3)*WD + x2))*CH + cin;
      #pragma unroll
      for (int k=0;k<14;++k){
        const float4* p = (const float4*)(base + (size_t)k*WD*CH);
        float4 rA = p[0], rB = p[1];
        #pragma unroll
        for (int dy=0; dy<7; ++dy){
          int yi = k - dy;
          if (yi >= 0 && yi < 8){
            acc[yi].x += rA.x*wa[dy].x + rA.y*wb4[dy].x;
            acc[yi].y += rA.z*wa[dy].y + rA.w*wb4[dy].y;
            acc[yi].z += rB.x*wa[dy].z + rB.y*wb4[dy].z;
            acc[yi].w += rB.z*wa[dy].w + rB.w*wb4[dy].w;
          }
        }
      }
    } else {
      #pragma unroll
      for (int k=0;k<14;++k){
        int yy = y0 + k - 3;
        float4 rA = {0,0,0,0}, rB = {0,0,0,0};
        if (vx && (unsigned)yy < HD){
          const float4* p = (const float4*)(S + ((size_t)((b*HD+yy)*WD + x2))*CH + cin);
          rA = p[0]; rB = p[1];
        }
        #pragma unroll
        for (int dy=0; dy<7; ++dy){
          int yi = k - dy;
          if (yi >= 0 && yi < 8){
            acc[yi].x += rA.x*wa[dy].x + rA.y*wb4[dy].x;
            acc[yi].y += rA.z*wa[dy].y + rA.w*wb4[dy].y;
            acc[yi].z += rB.x*wa[dy].z + rB.y*wb4[dy].z;
            acc[yi].w += rB.z*wa[dy].w + rB.w*wb4[dy].w;
          }
        }
      }
    }
  }
  float4 G2 = ((const float4*)g2)[lane],  B2 = ((const float4*)b2)[lane];
  float4 GF = ((const float4*)gf)[lane],  BF = ((const float4*)bfv)[lane];
  #pragma unroll 1
  for (int yi=0; yi<8; ++yi){
    float4 v;
    v.x = fmaxf(acc[yi].x, 0.f); v.y = fmaxf(acc[yi].y, 0.f);
    v.z = fmaxf(acc[yi].z, 0.f); v.w = fmaxf(acc[yi].w, 0.f);
    float s = v.x+v.y+v.z+v.w;
    float q = v.x*v.x+v.y*v.y+v.z*v.z+v.w*v.w;
    #pragma unroll
    for (int o=1;o<64;o<<=1){ s += __shfl_xor(s,o); q += __shfl_xor(q,o); }
    float mean = s*(1.f/CH);
    float r = rsqrtf(q*(1.f/CH) - mean*mean + 1e-5f);
    float4 w4;
    w4.x = (v.x-mean)*r*G2.x + B2.x;
    w4.y = (v.y-mean)*r*G2.y + B2.y;
    w4.z = (v.z-mean)*r*G2.z + B2.z;
    w4.w = (v.w-mean)*r*G2.w + B2.w;
    size_t n = (size_t)((b*HD + y0+yi)*WD + xx);
    ((float4*)(xc + n*CH))[lane] = w4;
    float s2 = w4.x+w4.y+w4.z+w4.w;
    float q2 = w4.x*w4.x+w4.y*w4.y+w4.z*w4.z+w4.w*w4.w;
    #pragma unroll
    for (int o=1;o<64;o<<=1){ s2 += __shfl_xor(s2,o); q2 += __shfl_xor(q2,o); }
    float m2 = s2*(1.f/CH);
    float r2 = rsqrtf(q2*(1.f/CH) - m2*m2 + 1e-5f);
    bf16x4 yv;
    yv[0] = f2bf((w4.x-m2)*r2*GF.x + BF.x);
    yv[1] = f2bf((w4.y-m2)*r2*GF.y + BF.y);
    yv[2] = f2bf((w4.z-m2)*r2*GF.z + BF.z);
    yv[3] = f2bf((w4.w-m2)*r2*GF.w + BF.w);
    ((bf16x4*)(ybuf + n*CH))[lane] = yv;
  }
}

// ---------------- window attention, fused qkv (per 8x8 window) ----------------
__global__ __launch_bounds__(256) void k_attn(const short* __restrict__ ybuf,
    const short* __restrict__ wqkv, const float* __restrict__ qkvb,
    short* __restrict__ obuf){
  __shared__ short yw[64][264];
  __shared__ short qs[64][40];
  __shared__ short ksm[64][40];
  __shared__ short vT[32][72];
  __shared__ short ps[64][72];
  int wid = blockIdx.x;
  int b = wid>>10, wy = (wid>>5)&31, wx = wid&31;
  int t = threadIdx.x, wv = t>>6, lane = t&63;
  int g = lane>>4, c = lane&15;
  {
    int row = t>>2, seg = t&3;
    size_t n = (size_t)(b*HD + wy*8 + (row>>3))*WD + wx*8 + (row&7);
    const uint4* s = (const uint4*)(ybuf + n*CH + seg*64);
    uint4* d = (uint4*)(&yw[row][seg*64]);
    #pragma unroll
    for (int i=0;i<8;++i) d[i] = s[i];
  }
  __syncthreads();
  bf16x8 afr[8];
  #pragma unroll
  for (int ks=0;ks<8;++ks)
    afr[ks] = *(const bf16x8*)(&yw[16*wv + c][ks*32 + g*8]);

  #pragma unroll 1
  for (int hd=0; hd<8; ++hd){
    f32x4 acc[6];
    #pragma unroll
    for (int nt=0;nt<6;++nt) acc[nt] = (f32x4){0.f,0.f,0.f,0.f};
    #pragma unroll
    for (int nt=0; nt<6; ++nt){
      const short* wp = wqkv + (size_t)(hd*96 + nt*16 + c)*256;
      #pragma unroll
      for (int ks=0; ks<8; ++ks){
        bf16x8 bf = *(const bf16x8*)(wp + ks*32 + g*8);
        acc[nt] = mfma_bf16(afr[ks], bf, acc[nt]);
      }
    }
    __syncthreads();   // prev head's PV reads of ps/vT done
    #pragma unroll
    for (int nt=0; nt<6; ++nt){
      float bias = qkvb[hd*96 + nt*16 + c];
      #pragma unroll
      for (int j=0;j<4;++j){
        short hv = f2bf(acc[nt][j] + bias);
        int tok = 16*wv + 4*g + j;
        if (nt<2)      qs[tok][nt*16 + c] = hv;
        else if (nt<4) ksm[tok][(nt-2)*16 + c] = hv;
        else           vT[(nt-4)*16 + c][tok] = hv;
      }
    }
    __syncthreads();
    // S = q @ k^T  (wave wv owns rows 16wv..16wv+15)
    f32x4 sv[4];
    bf16x8 qa = *(const bf16x8*)(&qs[16*wv + c][g*8]);
    #pragma unroll
    for (int nt=0;nt<4;++nt){
      bf16x8 kb = *(const bf16x8*)(&ksm[nt*16 + c][g*8]);
      f32x4 z = (f32x4){0.f,0.f,0.f,0.f};
      sv[nt] = mfma_bf16(qa, kb, z);
    }
    float inv[4];
    #pragma unroll
    for (int j=0;j<4;++j){
      float mx = fmaxf(fmaxf(sv[0][j],sv[1][j]), fmaxf(sv[2][j],sv[3][j]));
      #pragma unroll
      for (int o=1;o<16;o<<=1) mx = fmaxf(mx, __shfl_xor(mx, o));
      float sm = 0.f;
      #pragma unroll
      for (int nt=0;nt<4;++nt){
        float e = __expf((sv[nt][j]-mx)*0.17677669529663687f);
        sv[nt][j] = e; sm += e;
      }
      #pragma unroll
      for (int o=1;o<16;o<<=1) sm += __shfl_xor(sm, o);
      inv[j] = 1.f/sm;
    }
    #pragma unroll
    for (int nt=0;nt<4;++nt)
      #pragma unroll
      for (int j=0;j<4;++j)
        ps[16*wv + 4*g + j][nt*16 + c] = f2bf(sv[nt][j]);
    __syncthreads();
    // O = P @ V (unnormalized P, scale rows by inv afterwards)
    f32x4 ov[2];
    ov[0] = (f32x4){0.f,0.f,0.f,0.f}; ov[1] = (f32x4){0.f,0.f,0.f,0.f};
    #pragma unroll
    for (int k2=0;k2<2;++k2){
      bf16x8 pa = *(const bf16x8*)(&ps[16*wv + c][k2*32 + g*8]);
      #pragma unroll
      for (int nt=0;nt<2;++nt){
        bf16x8 vb = *(const bf16x8*)(&vT[nt*16 + c][k2*32 + g*8]);
        ov[nt] = mfma_bf16(pa, vb, ov[nt]);
      }
    }
    #pragma unroll
    for (int nt=0;nt<2;++nt)
      #pragma unroll
      for (int j=0;j<4;++j){
        int tok = 16*wv + 4*g + j;
        size_t n = (size_t)(b*HD + wy*8 + (tok>>3))*WD + wx*8 + (tok&7);
        obuf[n*CH + hd*32 + nt*16 + c] = f2bf(ov[nt][j]*inv[j]);
      }
  }
}

// ---------------- proj + bias + residual + relu + LN3 -> bf16 z ----------------
__global__ __launch_bounds__(256) void k_proj(const short* __restrict__ obuf,
    const short* __restrict__ wproj, const float* __restrict__ pb,
    const float* __restrict__ xc, const float* __restrict__ g3,
    const float* __restrict__ b3, short* __restrict__ zbuf){
  __shared__ short ao[64][264];
  __shared__ float redS[64][4];
  __shared__ float redQ[64][4];
  int blk = blockIdx.x, t = threadIdx.x;
  int wv = t>>6, lane = t&63, g = lane>>4, c = lane&15;
  size_t m0 = (size_t)blk*64;
  {
    int row = t>>2, seg = t&3;
    const uint4* s = (const uint4*)(obuf + (m0+row)*CH + seg*64);
    uint4* d = (uint4*)(&ao[row][seg*64]);
    #pragma unroll
    for (int i=0;i<8;++i) d[i] = s[i];
  }
  __syncthreads();
  f32x4 acc[4][4];
  #pragma unroll
  for (int mt=0;mt<4;++mt)
    #pragma unroll
    for (int nt=0;nt<4;++nt) acc[mt][nt] = (f32x4){0.f,0.f,0.f,0.f};
  #pragma unroll 1
  for (int ks=0; ks<8; ++ks){
    bf16x8 a[4];
    #pragma unroll
    for (int mt=0;mt<4;++mt) a[mt] = *(const bf16x8*)(&ao[mt*16+c][ks*32+g*8]);
    #pragma unroll
    for (int nt=0;nt<4;++nt){
      bf16x8 bfr = *(const bf16x8*)(wproj + (size_t)(wv*64 + nt*16 + c)*256 + ks*32 + g*8);
      #pragma unroll
      for (int mt=0;mt<4;++mt)
        acc[mt][nt] = mfma_bf16(a[mt], bfr, acc[mt][nt]);
    }
  }
  #pragma unroll
  for (int mt=0;mt<4;++mt){
    #pragma unroll
    for (int j=0;j<4;++j){
      int row_l = mt*16 + 4*g + j;
      float ps_ = 0.f, pq_ = 0.f;
      #pragma unroll
      for (int nt=0;nt<4;++nt){
        int col = wv*64 + nt*16 + c;
        float v = acc[mt][nt][j] + pb[col] + xc[(m0+row_l)*CH + col];
        v = fmaxf(v, 0.f);
        acc[mt][nt][j] = v;
        ps_ += v; pq_ += v*v;
      }
      #pragma unroll
      for (int o=1;o<16;o<<=1){ ps_ += __shfl_xor(ps_,o); pq_ += __shfl_xor(pq_,o); }
      if (c==0){ redS[row_l][wv] = ps_; redQ[row_l][wv] = pq_; }
    }
  }
  __syncthreads();
  #pragma unroll
  for (int mt=0;mt<4;++mt){
    #pragma unroll
    for (int j=0;j<4;++j){
      int row_l = mt*16 + 4*g + j;
      float st = redS[row_l][0]+redS[row_l][1]+redS[row_l][2]+redS[row_l][3];
      float qt = redQ[row_l][0]+redQ[row_l][1]+redQ[row_l][2]+redQ[row_l][3];
      float mean = st*(1.f/CH);
      float rs = rsqrtf(qt*(1.f/CH) - mean*mean + 1e-5f);
      #pragma unroll
      for (int nt=0;nt<4;++nt){
        int col = wv*64 + nt*16 + c;
        float y = (acc[mt][nt][j]-mean)*rs*g3[col] + b3[col];
        zbuf[(m0+row_l)*CH + col] = f2bf(y);
      }
    }
  }
}

// ---------------- fused MLP: gelu(z@w1^T+b1)@w2^T+b2 -> fp32 ----------------
__global__ __launch_bounds__(256) void k_mlp(const short* __restrict__ zbuf,
    const short* __restrict__ w1, const short* __restrict__ w2,
    const float* __restrict__ b1, const float* __restrict__ b2,
    float* __restrict__ bsa){
  __shared__ short zt[64][264];
  __shared__ short hid[64][136];
  int blk = blockIdx.x, t = threadIdx.x;
  int wv=t>>6, lane=t&63, g=lane>>4, c=lane&15;
  size_t m0 = (size_t)blk*64;
  {
    int row=t>>2, seg=t&3;
    const uint4* s = (const uint4*)(zbuf + (m0+row)*CH + seg*64);
    uint4* d = (uint4*)(&zt[row][seg*64]);
    #pragma unroll
    for (int i=0;i<8;++i) d[i] = s[i];
  }
  __syncthreads();
  f32x4 acc2[4][4];
  #pragma unroll
  for (int mt=0;mt<4;++mt)
    #pragma unroll
    for (int nt=0;nt<4;++nt) acc2[mt][nt] = (f32x4){0.f,0.f,0.f,0.f};
  #pragma unroll 1
  for (int hc=0; hc<8; ++hc){
    f32x4 a1[4][2];
    #pragma unroll
    for (int mt=0;mt<4;++mt){ a1[mt][0]=(f32x4){0.f,0.f,0.f,0.f}; a1[mt][1]=(f32x4){0.f,0.f,0.f,0.f}; }
    #pragma unroll 1
    for (int ks=0;ks<8;++ks){
      bf16x8 a[4];
      #pragma unroll
      for (int mt=0;mt<4;++mt) a[mt] = *(const bf16x8*)(&zt[mt*16+c][ks*32+g*8]);
      #pragma unroll
      for (int nl=0;nl<2;++nl){
        int o = hc*128 + (wv*2+nl)*16 + c;
        bf16x8 bfr = *(const bf16x8*)(w1 + (size_t)o*256 + ks*32 + g*8);
        #pragma unroll
        for (int mt=0;mt<4;++mt)
          a1[mt][nl] = mfma_bf16(a[mt], bfr, a1[mt][nl]);
      }
    }
    __syncthreads();   // prev GEMM2 reads of hid done
    #pragma unroll
    for (int mt=0;mt<4;++mt)
      #pragma unroll
      for (int nl=0;nl<2;++nl){
        int ol = (wv*2+nl)*16 + c;
        float bias = b1[hc*128 + ol];
        #pragma unroll
        for (int j=0;j<4;++j){
          float v = a1[mt][nl][j] + bias;
          float u = 0.7978845608f*(v + 0.044715f*v*v*v);
          float e = __expf(-2.f*fabsf(u));
          float th = (1.f-e)/(1.f+e);
          th = (u>=0.f)? th : -th;
          v = 0.5f*v*(1.f+th);
          hid[mt*16 + 4*g + j][ol] = f2bf(v);
        }
      }
    __syncthreads();
    #pragma unroll 1
    for (int k2=0;k2<4;++k2){
      bf16x8 a[4];
      #pragma unroll
      for (int mt=0;mt<4;++mt) a[mt] = *(const bf16x8*)(&hid[mt*16+c][k2*32+g*8]);
      #pragma unroll
      for (int nt=0;nt<4;++nt){
        bf16x8 bfr = *(const bf16x8*)(w2 + (size_t)(wv*64+nt*16+c)*1024 + hc*128 + k2*32 + g*8);
        #pragma unroll
        for (int mt=0;mt<4;++mt)
          acc2[mt][nt] = mfma_bf16(a[mt], bfr, acc2[mt][nt]);
      }
    }
    __syncthreads();
  }
  #pragma unroll
  for (int mt=0;mt<4;++mt)
    #pragma unroll
    for (int nt=0;nt<4;++nt){
      int col = wv*64 + nt*16 + c;
      #pragma unroll
      for (int j=0;j<4;++j){
        int row_l = mt*16 + 4*g + j;
        bsa[(m0+row_l)*CH + col] = acc2[mt][nt][j] + b2[col];
      }
    }
}

// ---------------- depthwise 7x7 + bias + relu (NHWC), transposed weights ----------------
__global__ __launch_bounds__(256) void k_dw7(const float* __restrict__ src,
    const float* __restrict__ wT, const float* __restrict__ bias, float* __restrict__ dst){
  // grid = 64 xg * 32 yb * 2 b = 4096 ; wave: one x, 8 y, 4 ch per lane
  int bid = blockIdx.x;
  int xg = bid & 63, yb = (bid>>6) & 31, b = bid>>11;
  int wv = threadIdx.x>>6, lane = threadIdx.x & 63;
  int xx = xg*4 + wv, y0 = yb*8;
  float4 bv = ((const float4*)bias)[lane];
  float4 acc[8];
  #pragma unroll
  for (int i=0;i<8;++i) acc[i] = bv;
  bool inty = (y0 >= 3) && (y0 <= HD-11);
  #pragma unroll 1
  for (int dx=0; dx<7; ++dx){
    int x2 = xx + dx - 3;
    bool vx = (unsigned)x2 < WD;
    float4 r[14];
    if (vx && inty){
      const float* base = src + ((size_t)((b*HD + y0-3)*WD + x2))*CH;
      #pragma unroll
      for (int k=0;k<14;++k)
        r[k] = ((const float4*)(base + (size_t)k*WD*CH))[lane];
    } else {
      #pragma unroll
      for (int k=0;k<14;++k){
        int yy = y0 + k - 3;
        if (vx && (unsigned)yy < HD)
          r[k] = ((const float4*)(src + ((size_t)((b*HD+yy)*WD + x2))*CH))[lane];
        else r[k] = float4{0,0,0,0};
      }
    }
    #pragma unroll
    for (int dy=0; dy<7; ++dy){
      int wi = dy*7 + dx;
      float4 wv4 = ((const float4*)(wT + wi*256))[lane];
      #pragma unroll
      for (int yi=0; yi<8; ++yi){
        acc[yi].x += r[yi+dy].x * wv4.x;
        acc[yi].y += r[yi+dy].y * wv4.y;
        acc[yi].z += r[yi+dy].z * wv4.z;
        acc[yi].w += r[yi+dy].w * wv4.w;
      }
    }
  }
  #pragma unroll
  for (int yi=0; yi<8; ++yi){
    float4 o;
    o.x = fmaxf(acc[yi].x, 0.f); o.y = fmaxf(acc[yi].y, 0.f);
    o.z = fmaxf(acc[yi].z, 0.f); o.w = fmaxf(acc[yi].w, 0.f);
    ((float4*)(dst + ((size_t)((b*HD+y0+yi)*WD + xx))*CH))[lane] = o;
  }
}

// ---------------- grouped 3x3 (64 groups of 4) + relu -> NCHW out ----------------
// lane = oc; wave loads full 256-ch pixel vectors coalesced (1KB/instr)
__global__ __launch_bounds__(256) void k_convf(const float* __restrict__ gsrc,
    const float* __restrict__ wTf, const float* __restrict__ bias, float* __restrict__ out){
  // grid = 64 xg * 32 yb * 2 b = 4096 ; wave: one x column, 8 y, lane = oc
  __shared__ float ot[4][8][65];
  int bid = blockIdx.x;
  int xg = bid & 63, yb = (bid>>6) & 31, b = bid>>11;
  int wv = threadIdx.x>>6, lane = threadIdx.x & 63;
  int xx = xg*4 + wv, y0 = yb*8;
  float bv = bias[lane];
  float acc[8];
  #pragma unroll
  for (int i=0;i<8;++i) acc[i] = 0.f;
  bool inty = (y0 >= 1) && (y0 <= HD-9);
  #pragma unroll 1
  for (int dx=0; dx<3; ++dx){
    int x2 = xx + dx - 1;
    bool vx = (unsigned)x2 < WD;
    float4 r[10];
    if (vx && inty){
      const float* base = gsrc + ((size_t)((b*HD + y0-1)*WD + x2))*CH;
      #pragma unroll
      for (int k=0;k<10;++k)
        r[k] = ((const float4*)(base + (size_t)k*WD*CH))[lane];
    } else {
      #pragma unroll
      for (int k=0;k<10;++k){
        int yy = y0 + k - 1;
        if (vx && (unsigned)yy < HD)
          r[k] = ((const float4*)(gsrc + ((size_t)((b*HD+yy)*WD + x2))*CH))[lane];
        else r[k] = float4{0,0,0,0};
      }
    }
    #pragma unroll
    for (int dy=0; dy<3; ++dy){
      float4 w4 = ((const float4*)(wTf + (dy*3+dx)*256))[lane];
      #pragma unroll
      for (int yi=0; yi<8; ++yi)
        acc[yi] += r[yi+dy].x*w4.x + r[yi+dy].y*w4.y + r[yi+dy].z*w4.z + r[yi+dy].w*w4.w;
    }
  }
  #pragma unroll
  for (int yi=0; yi<8; ++yi) ot[wv][yi][lane] = fmaxf(acc[yi] + bv, 0.f);
  __syncthreads();
  #pragma unroll
  for (int rep=0; rep<2; ++rep){
    int p = rep*256 + threadIdx.x;
    int oc = p>>3, yi = p&7;
    float4 v;
    v.x = ot[0][yi][oc]; v.y = ot[1][yi][oc]; v.z = ot[2][yi][oc]; v.w = ot[3][yi][oc];
    *(float4*)(out + (((size_t)(b*64+oc))*HD + y0+yi)*WD + xg*4) = v;
  }
}

extern "C" void kernel_launch(void* const* d_in, const int* in_sizes, int n_in,
                              void* d_out, int out_size, void* d_ws, size_t ws_size,
                              hipStream_t stream) {
  const float* x      = (const float*)d_in[0];
  const float* hbuf   = (const float*)d_in[1];
  const float* conv_w = (const float*)d_in[2];
  const float* conv_b = (const float*)d_in[3];
  const float* comb_w = (const float*)d_in[4];
  const float* comb_b = (const float*)d_in[5];
  const float* ln1_g  = (const float*)d_in[6];
  const float* ln1_b  = (const float*)d_in[7];
  const float* ln2_g  = (const float*)d_in[8];
  const float* ln2_b  = (const float*)d_in[9];
  const float* ln3_g  = (const float*)d_in[10];
  const float* ln3_b  = (const float*)d_in[11];
  const float* fsa_g  = (const float*)d_in[12];
  const float* fsa_b  = (const float*)d_in[13];
  const float* qkv_w  = (const float*)d_in[14];
  const float* qkv_b  = (const float*)d_in[15];
  const float* proj_w = (const float*)d_in[16];
  const float* proj_b = (const float*)d_in[17];
  const float* mlp_w1 = (const float*)d_in[18];
  const float* mlp_b1 = (const float*)d_in[19];
  const float* mlp_w2 = (const float*)d_in[20];
  const float* mlp_b2 = (const float*)d_in[21];
  const float* convg_w= (const float*)d_in[22];
  const float* convg_b= (const float*)d_in[23];
  const float* convh_w= (const float*)d_in[24];
  const float* convh_b= (const float*)d_in[25];
  const float* convf_w= (const float*)d_in[26];
  const float* convf_b= (const float*)d_in[27];
  float* out = (float*)d_out;
  char* ws = (char*)d_ws;

  // ws layout (bytes):
  // [0,134M)    xconv fp32  -> later: obuf bf16 [0,67M), zbuf bf16 [67M,134M)
  // [134M,268M) xc fp32     -> later: bsa fp32
  // [268M,335M) y bf16
  // [335M,469M) (free)      -> later: g fp32
  // [469762048) bf16 weights (786432 shorts)
  // [471334912) fp32 transposed dw/conv weights (52480 floats)
  float* xconv = (float*)(ws);
  short* obuf  = (short*)(ws);
  short* zbuf  = (short*)(ws + 67108864);
  float* xc    = (float*)(ws + 134217728);
  float* bsa   = (float*)(ws + 134217728);
  short* ybuf  = (short*)(ws + 268435456);
  float* gbuf  = (float*)(ws + 335544320);
  short* wb    = (short*)(ws + 469762048);
  float* wT    = (float*)(ws + 471334912);

  k_cvtw<<<3072,256,0,stream>>>(qkv_w, proj_w, mlp_w1, mlp_w2, wb);
  k_prepw<<<205,256,0,stream>>>(comb_w, convg_w, convh_w, convf_w, wT);
  k_conv3<<<8192,256,0,stream>>>(x, conv_w, conv_b, ln1_g, ln1_b, xconv);
  k_comb<<<4096,256,0,stream>>>(xconv, hbuf, wT, comb_b, ln2_g, ln2_b, fsa_g, fsa_b, xc, ybuf);
  k_attn<<<2048,256,0,stream>>>(ybuf, wb, qkv_b, obuf);
  k_proj<<<2048,256,0,stream>>>(obuf, wb+196608, proj_b, xc, ln3_g, ln3_b, zbuf);
  k_mlp<<<2048,256,0,stream>>>(zbuf, wb+262144, wb+524288, mlp_b1, mlp_b2, bsa);
  k_dw7<<<4096,256,0,stream>>>(bsa, wT+25088, convg_b, gbuf);
  k_dw7<<<4096,256,0,stream>>>(gbuf, wT+37632, convh_b, out + 8388608);
  k_convf<<<4096,256,0,stream>>>(gbuf, wT+50176, convf_b, out);
}

// Round 5
// 1655.827 us; speedup vs baseline: 1.4485x; 1.4485x over previous
//
#include <hip/hip_runtime.h>
#include <hip/hip_bf16.h>

#define HD 256
#define WD 256
#define CH 256
#define NB 2
#define NPIX (NB*HD*WD)

typedef __attribute__((ext_vector_type(4))) float f32x4;
typedef __attribute__((ext_vector_type(8))) short bf16x8;
typedef __attribute__((ext_vector_type(4))) short bf16x4;

__device__ __forceinline__ short f2bf(float f){
  unsigned u = __float_as_uint(f);
  u += 0x7fffu + ((u>>16)&1u);
  return (short)(u>>16);
}

__device__ __forceinline__ f32x4 mfma_bf16(bf16x8 a, bf16x8 b, f32x4 c){
  asm("v_mfma_f32_16x16x32_bf16 %0, %1, %2, %0" : "+v"(c) : "v"(a), "v"(b));
  return c;
}

// ---------------- weight fp32 -> bf16 ----------------
// layout (shorts): [0) qkv 196608 | [196608) proj 65536 | [262144) w1 262144 | [524288) w2 262144
__global__ __launch_bounds__(256) void k_cvtw(const float* __restrict__ qkvw,
    const float* __restrict__ projw, const float* __restrict__ w1,
    const float* __restrict__ w2, short* __restrict__ out){
  int i = blockIdx.x*256 + threadIdx.x;
  float v;
  if (i < 196608) v = qkvw[i];
  else if (i < 262144) v = projw[i-196608];
  else if (i < 524288) v = w1[i-262144];
  else v = w2[i-524288];
  out[i] = f2bf(v);
}

// ---------------- transpose conv weights to channel-minor ----------------
// wT layout (floats): [0) comb 49*512 (wi,i,o) | [25088) g 49*256 | [37632) h 49*256
//                     [50176) convf 9*256 (tap, oc*4+ic)
__global__ __launch_bounds__(256) void k_prepw(const float* __restrict__ combw,
    const float* __restrict__ gw, const float* __restrict__ hw,
    const float* __restrict__ fw, float* __restrict__ wT){
  int i = blockIdx.x*256 + threadIdx.x;
  if (i < 25088){
    int wi = i>>9, r = i&511, ii = r>>8, o = r&255;
    wT[i] = combw[o*98 + ii*49 + wi];
  } else if (i < 37632){
    int j = i-25088; int wi = j>>8, c = j&255;
    wT[i] = gw[c*49 + wi];
  } else if (i < 50176){
    int j = i-37632; int wi = j>>8, c = j&255;
    wT[i] = hw[c*49 + wi];
  } else if (i < 52480){
    int j = i-50176; int tap = j>>8, r = j&255, oc = r>>2, ic = r&3;
    wT[i] = fw[oc*36 + ic*9 + tap];
  }
}

// ---------------- depthwise 3x3 (NCHW in) + bias + relu + LN1 -> NHWC ----------------
__global__ __launch_bounds__(256) void k_conv3(const float* __restrict__ x,
    const float* __restrict__ w, const float* __restrict__ bias,
    const float* __restrict__ g1, const float* __restrict__ b1,
    float* __restrict__ out){
  // grid = 16 xb * 256 y * 2 b = 8192
  int bid = blockIdx.x;
  int xb = bid & 15, y = (bid>>4) & 255, b = bid>>12;
  int t = threadIdx.x;
  __shared__ float tile[16][268];
  int xx0 = xb*16;
  {
    int xi = t & 15, cg = t >> 4;
    int xxg = xx0 + xi;
    #pragma unroll
    for (int k=0;k<16;++k){
      int c = cg*16 + k;
      const float* xp = x + ((size_t)(b*CH + c)*HD)*WD;
      float acc = bias[c];
      #pragma unroll
      for (int dy=-1; dy<=1; ++dy){
        int yy = y+dy;
        if ((unsigned)yy >= HD) continue;
        #pragma unroll
        for (int dx=-1; dx<=1; ++dx){
          int x2 = xxg+dx;
          if ((unsigned)x2 >= WD) continue;
          acc += xp[yy*WD + x2] * w[c*9 + (dy+1)*3 + (dx+1)];
        }
      }
      tile[xi][c] = fmaxf(acc, 0.f);
    }
  }
  __syncthreads();
  {
    int px = t >> 4, cs = t & 15;
    float4 m[4];
    #pragma unroll
    for (int j=0;j<4;++j) m[j] = *(const float4*)(&tile[px][cs*16 + j*4]);
    float s = 0.f, q = 0.f;
    #pragma unroll
    for (int j=0;j<4;++j){
      s += m[j].x+m[j].y+m[j].z+m[j].w;
      q += m[j].x*m[j].x+m[j].y*m[j].y+m[j].z*m[j].z+m[j].w*m[j].w;
    }
    #pragma unroll
    for (int o=1;o<16;o<<=1){ s += __shfl_xor(s,o); q += __shfl_xor(q,o); }
    float mean = s*(1.f/CH);
    float r = rsqrtf(q*(1.f/CH) - mean*mean + 1e-5f);
    size_t n = (size_t)(b*HD + y)*WD + xx0 + px;
    float* op = out + n*CH + cs*16;
    #pragma unroll
    for (int j=0;j<4;++j){
      float4 G = *(const float4*)(g1 + cs*16 + j*4);
      float4 Bb = *(const float4*)(b1 + cs*16 + j*4);
      float4 o4;
      o4.x = (m[j].x-mean)*r*G.x + Bb.x;
      o4.y = (m[j].y-mean)*r*G.y + Bb.y;
      o4.z = (m[j].z-mean)*r*G.z + Bb.z;
      o4.w = (m[j].w-mean)*r*G.w + Bb.w;
      *(float4*)(op + j*4) = o4;
    }
  }
}

// ---------------- grouped 7x7 combine + relu + LN2 + fsaLN ----------------
// out channel o reads concat-channels 2o,2o+1; o<128 -> xconv, o>=128 -> h
__global__ __launch_bounds__(256) void k_comb(const float* __restrict__ xconv,
    const float* __restrict__ hbuf, const float* __restrict__ wT,
    const float* __restrict__ bias,
    const float* __restrict__ g2, const float* __restrict__ b2,
    const float* __restrict__ gf, const float* __restrict__ bfv,
    float* __restrict__ xc, short* __restrict__ ybuf){
  // grid = 64 xg * 64 yb * 2 b = 8192 ; wave: one x, 4 y, 4 out-ch per lane
  int bid = blockIdx.x;
  int xg = bid & 63, yb = (bid>>6) & 63, b = bid>>12;
  int wv = threadIdx.x>>6, lane = threadIdx.x & 63;
  int xx = xg*4 + wv, y0 = yb*4;
  const float* S = (lane < 32) ? xconv : hbuf;
  int cin = 8*(lane & 31);
  float4 bv = ((const float4*)bias)[lane];
  float4 acc[4];
  #pragma unroll
  for (int i=0;i<4;++i) acc[i] = bv;
  bool inty = (y0 >= 3) && (y0 <= HD-7);
  #pragma unroll 1
  for (int dx=0; dx<7; ++dx){
    int x2 = xx + dx - 3;
    bool vx = (unsigned)x2 < WD;
    float4 rA[10], rB[10];
    if (vx && inty){
      const float* base = S + ((size_t)((b*HD + y0-3)*WD + x2))*CH + cin;
      #pragma unroll
      for (int k=0;k<10;++k){
        const float4* p = (const float4*)(base + (size_t)k*WD*CH);
        rA[k] = p[0]; rB[k] = p[1];
      }
    } else {
      #pragma unroll
      for (int k=0;k<10;++k){
        int yy = y0 + k - 3;
        if (vx && (unsigned)yy < HD){
          const float4* p = (const float4*)(S + ((size_t)((b*HD+yy)*WD + x2))*CH + cin);
          rA[k] = p[0]; rB[k] = p[1];
        } else {
          rA[k] = float4{0,0,0,0}; rB[k] = float4{0,0,0,0};
        }
      }
    }
    #pragma unroll
    for (int dy=0; dy<7; ++dy){
      int wi = dy*7 + dx;
      float4 wa = ((const float4*)(wT + wi*512))[lane];
      float4 wb4 = ((const float4*)(wT + wi*512 + 256))[lane];
      #pragma unroll
      for (int yi=0; yi<4; ++yi){
        int k = yi + dy;
        acc[yi].x += rA[k].x*wa.x + rA[k].y*wb4.x;
        acc[yi].y += rA[k].z*wa.y + rA[k].w*wb4.y;
        acc[yi].z += rB[k].x*wa.z + rB[k].y*wb4.z;
        acc[yi].w += rB[k].z*wa.w + rB[k].w*wb4.w;
      }
    }
  }
  float4 G2 = ((const float4*)g2)[lane],  B2 = ((const float4*)b2)[lane];
  float4 GF = ((const float4*)gf)[lane],  BF = ((const float4*)bfv)[lane];
  #pragma unroll
  for (int yi=0; yi<4; ++yi){
    float4 v;
    v.x = fmaxf(acc[yi].x, 0.f); v.y = fmaxf(acc[yi].y, 0.f);
    v.z = fmaxf(acc[yi].z, 0.f); v.w = fmaxf(acc[yi].w, 0.f);
    float s = v.x+v.y+v.z+v.w;
    float q = v.x*v.x+v.y*v.y+v.z*v.z+v.w*v.w;
    #pragma unroll
    for (int o=1;o<64;o<<=1){ s += __shfl_xor(s,o); q += __shfl_xor(q,o); }
    float mean = s*(1.f/CH);
    float r = rsqrtf(q*(1.f/CH) - mean*mean + 1e-5f);
    float4 w4;
    w4.x = (v.x-mean)*r*G2.x + B2.x;
    w4.y = (v.y-mean)*r*G2.y + B2.y;
    w4.z = (v.z-mean)*r*G2.z + B2.z;
    w4.w = (v.w-mean)*r*G2.w + B2.w;
    size_t n = (size_t)((b*HD + y0+yi)*WD + xx);
    ((float4*)(xc + n*CH))[lane] = w4;
    float s2 = w4.x+w4.y+w4.z+w4.w;
    float q2 = w4.x*w4.x+w4.y*w4.y+w4.z*w4.z+w4.w*w4.w;
    #pragma unroll
    for (int o=1;o<64;o<<=1){ s2 += __shfl_xor(s2,o); q2 += __shfl_xor(q2,o); }
    float m2 = s2*(1.f/CH);
    float r2 = rsqrtf(q2*(1.f/CH) - m2*m2 + 1e-5f);
    bf16x4 yv;
    yv[0] = f2bf((w4.x-m2)*r2*GF.x + BF.x);
    yv[1] = f2bf((w4.y-m2)*r2*GF.y + BF.y);
    yv[2] = f2bf((w4.z-m2)*r2*GF.z + BF.z);
    yv[3] = f2bf((w4.w-m2)*r2*GF.w + BF.w);
    ((bf16x4*)(ybuf + n*CH))[lane] = yv;
  }
}

// ---------------- window attention + fused proj/residual/LN3 (per 8x8 window) ----------------
__global__ __launch_bounds__(256) void k_attn(const short* __restrict__ ybuf,
    const short* __restrict__ wqkv, const float* __restrict__ qkvb,
    const short* __restrict__ wproj, const float* __restrict__ pb,
    const float* __restrict__ xc, const float* __restrict__ g3,
    const float* __restrict__ b3, short* __restrict__ zbuf){
  __shared__ short yw[64][264];
  __shared__ short qs[64][40];
  __shared__ short ksm[64][40];
  __shared__ short vT[32][72];
  __shared__ short ps[64][72];
  __shared__ float redS[64][4];
  __shared__ float redQ[64][4];
  int wid = blockIdx.x;
  int b = wid>>10, wy = (wid>>5)&31, wx = wid&31;
  int t = threadIdx.x, wv = t>>6, lane = t&63;
  int g = lane>>4, c = lane&15;
  {
    int row = t>>2, seg = t&3;
    size_t n = (size_t)(b*HD + wy*8 + (row>>3))*WD + wx*8 + (row&7);
    const uint4* s = (const uint4*)(ybuf + n*CH + seg*64);
    uint4* d = (uint4*)(&yw[row][seg*64]);
    #pragma unroll
    for (int i=0;i<8;++i) d[i] = s[i];
  }
  __syncthreads();
  bf16x8 afr[8];
  #pragma unroll
  for (int ks=0;ks<8;++ks)
    afr[ks] = *(const bf16x8*)(&yw[16*wv + c][ks*32 + g*8]);

  #pragma unroll 1
  for (int hd=0; hd<8; ++hd){
    f32x4 acc[6];
    #pragma unroll
    for (int nt=0;nt<6;++nt) acc[nt] = (f32x4){0.f,0.f,0.f,0.f};
    #pragma unroll
    for (int nt=0; nt<6; ++nt){
      const short* wp = wqkv + (size_t)(hd*96 + nt*16 + c)*256;
      #pragma unroll
      for (int ks=0; ks<8; ++ks){
        bf16x8 bf = *(const bf16x8*)(wp + ks*32 + g*8);
        acc[nt] = mfma_bf16(afr[ks], bf, acc[nt]);
      }
    }
    __syncthreads();   // prev head's PV reads of ps/vT done (and yw o-writes)
    #pragma unroll
    for (int nt=0; nt<6; ++nt){
      float bias = qkvb[hd*96 + nt*16 + c];
      #pragma unroll
      for (int j=0;j<4;++j){
        short hv = f2bf(acc[nt][j] + bias);
        int tok = 16*wv + 4*g + j;
        if (nt<2)      qs[tok][nt*16 + c] = hv;
        else if (nt<4) ksm[tok][(nt-2)*16 + c] = hv;
        else           vT[(nt-4)*16 + c][tok] = hv;
      }
    }
    __syncthreads();
    // S = q @ k^T  (wave wv owns rows 16wv..16wv+15)
    f32x4 sv[4];
    bf16x8 qa = *(const bf16x8*)(&qs[16*wv + c][g*8]);
    #pragma unroll
    for (int nt=0;nt<4;++nt){
      bf16x8 kb = *(const bf16x8*)(&ksm[nt*16 + c][g*8]);
      f32x4 z = (f32x4){0.f,0.f,0.f,0.f};
      sv[nt] = mfma_bf16(qa, kb, z);
    }
    float inv[4];
    #pragma unroll
    for (int j=0;j<4;++j){
      float mx = fmaxf(fmaxf(sv[0][j],sv[1][j]), fmaxf(sv[2][j],sv[3][j]));
      #pragma unroll
      for (int o=1;o<16;o<<=1) mx = fmaxf(mx, __shfl_xor(mx, o));
      float sm = 0.f;
      #pragma unroll
      for (int nt=0;nt<4;++nt){
        float e = __expf((sv[nt][j]-mx)*0.17677669529663687f);
        sv[nt][j] = e; sm += e;
      }
      #pragma unroll
      for (int o=1;o<16;o<<=1) sm += __shfl_xor(sm, o);
      inv[j] = 1.f/sm;
    }
    #pragma unroll
    for (int nt=0;nt<4;++nt)
      #pragma unroll
      for (int j=0;j<4;++j)
        ps[16*wv + 4*g + j][nt*16 + c] = f2bf(sv[nt][j]);
    __syncthreads();
    // O = P @ V (unnormalized P, scale rows by inv afterwards) -> yw (input tile is dead)
    f32x4 ov[2];
    ov[0] = (f32x4){0.f,0.f,0.f,0.f}; ov[1] = (f32x4){0.f,0.f,0.f,0.f};
    #pragma unroll
    for (int k2=0;k2<2;++k2){
      bf16x8 pa = *(const bf16x8*)(&ps[16*wv + c][k2*32 + g*8]);
      #pragma unroll
      for (int nt=0;nt<2;++nt){
        bf16x8 vb = *(const bf16x8*)(&vT[nt*16 + c][k2*32 + g*8]);
        ov[nt] = mfma_bf16(pa, vb, ov[nt]);
      }
    }
    #pragma unroll
    for (int nt=0;nt<2;++nt)
      #pragma unroll
      for (int j=0;j<4;++j){
        int tok = 16*wv + 4*g + j;
        yw[tok][hd*32 + nt*16 + c] = f2bf(ov[nt][j]*inv[j]);
      }
  }
  __syncthreads();   // all heads' O in yw
  // ---- proj GEMM: z = LN3(relu(O @ Wp^T + pb + xc)) ----
  f32x4 acc[4][4];
  #pragma unroll
  for (int mt=0;mt<4;++mt)
    #pragma unroll
    for (int nt=0;nt<4;++nt) acc[mt][nt] = (f32x4){0.f,0.f,0.f,0.f};
  #pragma unroll 1
  for (int ks=0; ks<8; ++ks){
    bf16x8 a[4];
    #pragma unroll
    for (int mt=0;mt<4;++mt) a[mt] = *(const bf16x8*)(&yw[mt*16+c][ks*32+g*8]);
    #pragma unroll
    for (int nt=0;nt<4;++nt){
      bf16x8 bfr = *(const bf16x8*)(wproj + (size_t)(wv*64 + nt*16 + c)*256 + ks*32 + g*8);
      #pragma unroll
      for (int mt=0;mt<4;++mt)
        acc[mt][nt] = mfma_bf16(a[mt], bfr, acc[mt][nt]);
    }
  }
  #pragma unroll
  for (int mt=0;mt<4;++mt){
    #pragma unroll
    for (int j=0;j<4;++j){
      int row_l = mt*16 + 4*g + j;
      size_t n = (size_t)(b*HD + wy*8 + (row_l>>3))*WD + wx*8 + (row_l&7);
      float ps_ = 0.f, pq_ = 0.f;
      #pragma unroll
      for (int nt=0;nt<4;++nt){
        int col = wv*64 + nt*16 + c;
        float v = acc[mt][nt][j] + pb[col] + xc[n*CH + col];
        v = fmaxf(v, 0.f);
        acc[mt][nt][j] = v;
        ps_ += v; pq_ += v*v;
      }
      #pragma unroll
      for (int o=1;o<16;o<<=1){ ps_ += __shfl_xor(ps_,o); pq_ += __shfl_xor(pq_,o); }
      if (c==0){ redS[row_l][wv] = ps_; redQ[row_l][wv] = pq_; }
    }
  }
  __syncthreads();
  #pragma unroll
  for (int mt=0;mt<4;++mt){
    #pragma unroll
    for (int j=0;j<4;++j){
      int row_l = mt*16 + 4*g + j;
      size_t n = (size_t)(b*HD + wy*8 + (row_l>>3))*WD + wx*8 + (row_l&7);
      float st = redS[row_l][0]+redS[row_l][1]+redS[row_l][2]+redS[row_l][3];
      float qt = redQ[row_l][0]+redQ[row_l][1]+redQ[row_l][2]+redQ[row_l][3];
      float mean = st*(1.f/CH);
      float rs = rsqrtf(qt*(1.f/CH) - mean*mean + 1e-5f);
      #pragma unroll
      for (int nt=0;nt<4;++nt){
        int col = wv*64 + nt*16 + c;
        float y = (acc[mt][nt][j]-mean)*rs*g3[col] + b3[col];
        zbuf[n*CH + col] = f2bf(y);
      }
    }
  }
}

// ---------------- fused MLP: gelu(z@w1^T+b1)@w2^T+b2 -> fp32 ----------------
__global__ __launch_bounds__(256) void k_mlp(const short* __restrict__ zbuf,
    const short* __restrict__ w1, const short* __restrict__ w2,
    const float* __restrict__ b1, const float* __restrict__ b2,
    float* __restrict__ bsa){
  __shared__ short zt[64][264];
  __shared__ short hid[64][136];
  int blk = blockIdx.x, t = threadIdx.x;
  int wv=t>>6, lane=t&63, g=lane>>4, c=lane&15;
  size_t m0 = (size_t)blk*64;
  {
    int row=t>>2, seg=t&3;
    const uint4* s = (const uint4*)(zbuf + (m0+row)*CH + seg*64);
    uint4* d = (uint4*)(&zt[row][seg*64]);
    #pragma unroll
    for (int i=0;i<8;++i) d[i] = s[i];
  }
  __syncthreads();
  f32x4 acc2[4][4];
  #pragma unroll
  for (int mt=0;mt<4;++mt)
    #pragma unroll
    for (int nt=0;nt<4;++nt) acc2[mt][nt] = (f32x4){0.f,0.f,0.f,0.f};
  #pragma unroll 1
  for (int hc=0; hc<8; ++hc){
    f32x4 a1[4][2];
    #pragma unroll
    for (int mt=0;mt<4;++mt){ a1[mt][0]=(f32x4){0.f,0.f,0.f,0.f}; a1[mt][1]=(f32x4){0.f,0.f,0.f,0.f}; }
    #pragma unroll 1
    for (int ks=0;ks<8;++ks){
      bf16x8 a[4];
      #pragma unroll
      for (int mt=0;mt<4;++mt) a[mt] = *(const bf16x8*)(&zt[mt*16+c][ks*32+g*8]);
      #pragma unroll
      for (int nl=0;nl<2;++nl){
        int o = hc*128 + (wv*2+nl)*16 + c;
        bf16x8 bfr = *(const bf16x8*)(w1 + (size_t)o*256 + ks*32 + g*8);
        #pragma unroll
        for (int mt=0;mt<4;++mt)
          a1[mt][nl] = mfma_bf16(a[mt], bfr, a1[mt][nl]);
      }
    }
    __syncthreads();   // prev GEMM2 reads of hid done
    #pragma unroll
    for (int mt=0;mt<4;++mt)
      #pragma unroll
      for (int nl=0;nl<2;++nl){
        int ol = (wv*2+nl)*16 + c;
        float bias = b1[hc*128 + ol];
        #pragma unroll
        for (int j=0;j<4;++j){
          float v = a1[mt][nl][j] + bias;
          float u = 0.7978845608f*(v + 0.044715f*v*v*v);
          float e = __expf(-2.f*fabsf(u));
          float th = (1.f-e)/(1.f+e);
          th = (u>=0.f)? th : -th;
          v = 0.5f*v*(1.f+th);
          hid[mt*16 + 4*g + j][ol] = f2bf(v);
        }
      }
    __syncthreads();
    #pragma unroll 1
    for (int k2=0;k2<4;++k2){
      bf16x8 a[4];
      #pragma unroll
      for (int mt=0;mt<4;++mt) a[mt] = *(const bf16x8*)(&hid[mt*16+c][k2*32+g*8]);
      #pragma unroll
      for (int nt=0;nt<4;++nt){
        bf16x8 bfr = *(const bf16x8*)(w2 + (size_t)(wv*64+nt*16+c)*1024 + hc*128 + k2*32 + g*8);
        #pragma unroll
        for (int mt=0;mt<4;++mt)
          acc2[mt][nt] = mfma_bf16(a[mt], bfr, acc2[mt][nt]);
      }
    }
    __syncthreads();
  }
  #pragma unroll
  for (int mt=0;mt<4;++mt)
    #pragma unroll
    for (int nt=0;nt<4;++nt){
      int col = wv*64 + nt*16 + c;
      #pragma unroll
      for (int j=0;j<4;++j){
        int row_l = mt*16 + 4*g + j;
        bsa[(m0+row_l)*CH + col] = acc2[mt][nt][j] + b2[col];
      }
    }
}

// ---------------- depthwise 7x7 + bias + relu (NHWC), transposed weights ----------------
__global__ __launch_bounds__(256) void k_dw7(const float* __restrict__ src,
    const float* __restrict__ wT, const float* __restrict__ bias, float* __restrict__ dst){
  // grid = 64 xg * 32 yb * 2 b = 4096 ; wave: one x, 8 y, 4 ch per lane
  int bid = blockIdx.x;
  int xg = bid & 63, yb = (bid>>6) & 31, b = bid>>11;
  int wv = threadIdx.x>>6, lane = threadIdx.x & 63;
  int xx = xg*4 + wv, y0 = yb*8;
  float4 bv = ((const float4*)bias)[lane];
  float4 acc[8];
  #pragma unroll
  for (int i=0;i<8;++i) acc[i] = bv;
  bool inty = (y0 >= 3) && (y0 <= HD-11);
  #pragma unroll 1
  for (int dx=0; dx<7; ++dx){
    int x2 = xx + dx - 3;
    bool vx = (unsigned)x2 < WD;
    float4 r[14];
    if (vx && inty){
      const float* base = src + ((size_t)((b*HD + y0-3)*WD + x2))*CH;
      #pragma unroll
      for (int k=0;k<14;++k)
        r[k] = ((const float4*)(base + (size_t)k*WD*CH))[lane];
    } else {
      #pragma unroll
      for (int k=0;k<14;++k){
        int yy = y0 + k - 3;
        if (vx && (unsigned)yy < HD)
          r[k] = ((const float4*)(src + ((size_t)((b*HD+yy)*WD + x2))*CH))[lane];
        else r[k] = float4{0,0,0,0};
      }
    }
    #pragma unroll
    for (int dy=0; dy<7; ++dy){
      int wi = dy*7 + dx;
      float4 wv4 = ((const float4*)(wT + wi*256))[lane];
      #pragma unroll
      for (int yi=0; yi<8; ++yi){
        acc[yi].x += r[yi+dy].x * wv4.x;
        acc[yi].y += r[yi+dy].y * wv4.y;
        acc[yi].z += r[yi+dy].z * wv4.z;
        acc[yi].w += r[yi+dy].w * wv4.w;
      }
    }
  }
  #pragma unroll
  for (int yi=0; yi<8; ++yi){
    float4 o;
    o.x = fmaxf(acc[yi].x, 0.f); o.y = fmaxf(acc[yi].y, 0.f);
    o.z = fmaxf(acc[yi].z, 0.f); o.w = fmaxf(acc[yi].w, 0.f);
    ((float4*)(dst + ((size_t)((b*HD+y0+yi)*WD + xx))*CH))[lane] = o;
  }
}

// ---------------- grouped 3x3 (64 groups of 4) + relu -> NCHW out ----------------
// lane = oc; wave loads full 256-ch pixel vectors coalesced (1KB/instr)
__global__ __launch_bounds__(256) void k_convf(const float* __restrict__ gsrc,
    const float* __restrict__ wTf, const float* __restrict__ bias, float* __restrict__ out){
  // grid = 64 xg * 32 yb * 2 b = 4096 ; wave: one x column, 8 y, lane = oc
  __shared__ float ot[4][8][65];
  int bid = blockIdx.x;
  int xg = bid & 63, yb = (bid>>6) & 31, b = bid>>11;
  int wv = threadIdx.x>>6, lane = threadIdx.x & 63;
  int xx = xg*4 + wv, y0 = yb*8;
  float bv = bias[lane];
  float acc[8];
  #pragma unroll
  for (int i=0;i<8;++i) acc[i] = 0.f;
  bool inty = (y0 >= 1) && (y0 <= HD-9);
  #pragma unroll 1
  for (int dx=0; dx<3; ++dx){
    int x2 = xx + dx - 1;
    bool vx = (unsigned)x2 < WD;
    float4 r[10];
    if (vx && inty){
      const float* base = gsrc + ((size_t)((b*HD + y0-1)*WD + x2))*CH;
      #pragma unroll
      for (int k=0;k<10;++k)
        r[k] = ((const float4*)(base + (size_t)k*WD*CH))[lane];
    } else {
      #pragma unroll
      for (int k=0;k<10;++k){
        int yy = y0 + k - 1;
        if (vx && (unsigned)yy < HD)
          r[k] = ((const float4*)(gsrc + ((size_t)((b*HD+yy)*WD + x2))*CH))[lane];
        else r[k] = float4{0,0,0,0};
      }
    }
    #pragma unroll
    for (int dy=0; dy<3; ++dy){
      float4 w4 = ((const float4*)(wTf + (dy*3+dx)*256))[lane];
      #pragma unroll
      for (int yi=0; yi<8; ++yi)
        acc[yi] += r[yi+dy].x*w4.x + r[yi+dy].y*w4.y + r[yi+dy].z*w4.z + r[yi+dy].w*w4.w;
    }
  }
  #pragma unroll
  for (int yi=0; yi<8; ++yi) ot[wv][yi][lane] = fmaxf(acc[yi] + bv, 0.f);
  __syncthreads();
  #pragma unroll
  for (int rep=0; rep<2; ++rep){
    int p = rep*256 + threadIdx.x;
    int oc = p>>3, yi = p&7;
    float4 v;
    v.x = ot[0][yi][oc]; v.y = ot[1][yi][oc]; v.z = ot[2][yi][oc]; v.w = ot[3][yi][oc];
    *(float4*)(out + (((size_t)(b*64+oc))*HD + y0+yi)*WD + xg*4) = v;
  }
}

extern "C" void kernel_launch(void* const* d_in, const int* in_sizes, int n_in,
                              void* d_out, int out_size, void* d_ws, size_t ws_size,
                              hipStream_t stream) {
  const float* x      = (const float*)d_in[0];
  const float* hbuf   = (const float*)d_in[1];
  const float* conv_w = (const float*)d_in[2];
  const float* conv_b = (const float*)d_in[3];
  const float* comb_w = (const float*)d_in[4];
  const float* comb_b = (const float*)d_in[5];
  const float* ln1_g  = (const float*)d_in[6];
  const float* ln1_b  = (const float*)d_in[7];
  const float* ln2_g  = (const float*)d_in[8];
  const float* ln2_b  = (const float*)d_in[9];
  const float* ln3_g  = (const float*)d_in[10];
  const float* ln3_b  = (const float*)d_in[11];
  const float* fsa_g  = (const float*)d_in[12];
  const float* fsa_b  = (const float*)d_in[13];
  const float* qkv_w  = (const float*)d_in[14];
  const float* qkv_b  = (const float*)d_in[15];
  const float* proj_w = (const float*)d_in[16];
  const float* proj_b = (const float*)d_in[17];
  const float* mlp_w1 = (const float*)d_in[18];
  const float* mlp_b1 = (const float*)d_in[19];
  const float* mlp_w2 = (const float*)d_in[20];
  const float* mlp_b2 = (const float*)d_in[21];
  const float* convg_w= (const float*)d_in[22];
  const float* convg_b= (const float*)d_in[23];
  const float* convh_w= (const float*)d_in[24];
  const float* convh_b= (const float*)d_in[25];
  const float* convf_w= (const float*)d_in[26];
  const float* convf_b= (const float*)d_in[27];
  float* out = (float*)d_out;
  char* ws = (char*)d_ws;

  // ws layout (bytes):
  // [0,134M)    xconv fp32  -> later: zbuf bf16 [67M,134M)
  // [134M,268M) xc fp32     -> later: bsa fp32
  // [268M,335M) y bf16
  // [335M,469M) (free)      -> later: g fp32
  // [469762048) bf16 weights (786432 shorts)
  // [471334912) fp32 transposed dw/conv weights (52480 floats)
  float* xconv = (float*)(ws);
  short* zbuf  = (short*)(ws + 67108864);
  float* xc    = (float*)(ws + 134217728);
  float* bsa   = (float*)(ws + 134217728);
  short* ybuf  = (short*)(ws + 268435456);
  float* gbuf  = (float*)(ws + 335544320);
  short* wb    = (short*)(ws + 469762048);
  float* wT    = (float*)(ws + 471334912);

  k_cvtw<<<3072,256,0,stream>>>(qkv_w, proj_w, mlp_w1, mlp_w2, wb);
  k_prepw<<<205,256,0,stream>>>(comb_w, convg_w, convh_w, convf_w, wT);
  k_conv3<<<8192,256,0,stream>>>(x, conv_w, conv_b, ln1_g, ln1_b, xconv);
  k_comb<<<8192,256,0,stream>>>(xconv, hbuf, wT, comb_b, ln2_g, ln2_b, fsa_g, fsa_b, xc, ybuf);
  k_attn<<<2048,256,0,stream>>>(ybuf, wb, qkv_b, wb+196608, proj_b, xc, ln3_g, ln3_b, zbuf);
  k_mlp<<<2048,256,0,stream>>>(zbuf, wb+262144, wb+524288, mlp_b1, mlp_b2, bsa);
  k_dw7<<<4096,256,0,stream>>>(bsa, wT+25088, convg_b, gbuf);
  k_dw7<<<4096,256,0,stream>>>(gbuf, wT+37632, convh_b, out + 8388608);
  k_convf<<<4096,256,0,stream>>>(gbuf, wT+50176, convf_b, out);
}